// Round 1
// baseline (594.755 us; speedup 1.0000x reference)
//
#include <hip/hip_runtime.h>
#include <math.h>

#define T 2048
#define B 32
#define N 1024

__device__ __forceinline__ float fast_tanh(float x) {
    // 1 - 2/(e^{2x}+1): saturates correctly at +/-1, no NaN at overflow
    float e = __expf(2.0f * x);
    return 1.0f - 2.0f / (e + 1.0f);
}

__device__ __forceinline__ float wave_reduce_sum(float v) {
    #pragma unroll
    for (int off = 32; off > 0; off >>= 1) v += __shfl_down(v, off, 64);
    return v;
}

// dec[b][i] = sum_j hx[b][j] * Ws_w[i][j] + Ws_b[i]
__global__ void dec_feature_kernel(const float* __restrict__ hx,
                                   const float* __restrict__ Ws_w,
                                   const float* __restrict__ Ws_b,
                                   float* __restrict__ dec) {
    int w = blockIdx.x * 4 + (threadIdx.x >> 6);
    int lane = threadIdx.x & 63;
    int i = w >> 5;       // Ws_w row — 8 consecutive blocks share a row (L1/L2 hot)
    int b = w & 31;
    const float4* wr = (const float4*)(Ws_w + (size_t)i * N);
    const float4* hr = (const float4*)(hx + (size_t)b * N);
    float acc = 0.f;
    #pragma unroll
    for (int k = 0; k < 4; ++k) {
        float4 a = wr[k * 64 + lane];
        float4 h = hr[k * 64 + lane];
        acc += a.x * h.x + a.y * h.y + a.z * h.z + a.w * h.w;
    }
    acc = wave_reduce_sum(acc);
    if (lane == 0) dec[(size_t)b * N + i] = acc + Ws_b[i];
}

// scores[b][t] = sum_n tanh(ef[t][b][n] + dec[b][n]) * v_w[n] + v_b
__global__ void scores_kernel(const float* __restrict__ ef,
                              const float* __restrict__ dec,
                              const float* __restrict__ v_w,
                              const float* __restrict__ v_b,
                              float* __restrict__ scores) {
    int w = blockIdx.x * 4 + (threadIdx.x >> 6);  // w = t*B + b, matches ef flat layout
    int lane = threadIdx.x & 63;
    int t = w >> 5;
    int b = w & 31;
    const float4* e4 = (const float4*)(ef + (size_t)w * N);
    const float4* d4 = (const float4*)(dec + (size_t)b * N);
    const float4* v4 = (const float4*)v_w;
    float acc = 0.f;
    #pragma unroll
    for (int k = 0; k < 4; ++k) {
        float4 e = e4[k * 64 + lane];
        float4 d = d4[k * 64 + lane];
        float4 v = v4[k * 64 + lane];
        acc += fast_tanh(e.x + d.x) * v.x + fast_tanh(e.y + d.y) * v.y
             + fast_tanh(e.z + d.z) * v.z + fast_tanh(e.w + d.w) * v.w;
    }
    acc = wave_reduce_sum(acc);
    if (lane == 0) scores[(size_t)b * T + t] = acc + v_b[0];
}

// attn[b][t] = softmax_t(scores[b]) * mask[b][t]
__global__ void softmax_kernel(const float* __restrict__ scores,
                               const float* __restrict__ mask,
                               float* __restrict__ attn) {
    int b = blockIdx.x;
    int tid = threadIdx.x;
    int lane = tid & 63, wid = tid >> 6;
    float s[8];
    float m = -1e30f;
    #pragma unroll
    for (int k = 0; k < 8; ++k) {
        s[k] = scores[(size_t)b * T + tid + k * 256];
        m = fmaxf(m, s[k]);
    }
    __shared__ float redm[4], reds[4];
    #pragma unroll
    for (int off = 32; off > 0; off >>= 1) m = fmaxf(m, __shfl_down(m, off, 64));
    if (lane == 0) redm[wid] = m;
    __syncthreads();
    m = fmaxf(fmaxf(redm[0], redm[1]), fmaxf(redm[2], redm[3]));
    float sum = 0.f;
    #pragma unroll
    for (int k = 0; k < 8; ++k) { s[k] = __expf(s[k] - m); sum += s[k]; }
    sum = wave_reduce_sum(sum);
    if (lane == 0) reds[wid] = sum;
    __syncthreads();
    float inv = 1.0f / (reds[0] + reds[1] + reds[2] + reds[3]);
    #pragma unroll
    for (int k = 0; k < 8; ++k)
        attn[(size_t)b * T + tid + k * 256] =
            s[k] * inv * mask[(size_t)b * T + tid + k * 256];
}

// content[b][n] += sum_{t in chunk} attn[b][t] * eo[t][b][n]
__global__ void content_kernel(const float* __restrict__ eo,
                               const float* __restrict__ attn,
                               float* __restrict__ content) {
    int b = blockIdx.y;
    int t0 = blockIdx.x * 16;
    int tid = threadIdx.x;
    float4 acc = {0.f, 0.f, 0.f, 0.f};
    const float4* base = (const float4*)eo;
    #pragma unroll 4
    for (int tt = 0; tt < 16; ++tt) {
        int t = t0 + tt;
        float a = attn[(size_t)b * T + t];
        float4 e = base[((size_t)t * B + b) * (N / 4) + tid];
        acc.x += a * e.x; acc.y += a * e.y; acc.z += a * e.z; acc.w += a * e.w;
    }
    float* c = content + (size_t)b * N + tid * 4;
    atomicAdd(c + 0, acc.x);
    atomicAdd(c + 1, acc.y);
    atomicAdd(c + 2, acc.z);
    atomicAdd(c + 3, acc.w);
}

// out[b][i] = tanh( dot(content[b], lin_w[i][0:N]) + dot(hx[b], lin_w[i][N:2N]) + lin_b[i] )
__global__ void out_kernel(const float* __restrict__ content,
                           const float* __restrict__ hx,
                           const float* __restrict__ lin_w,
                           const float* __restrict__ lin_b,
                           float* __restrict__ out) {
    int w = blockIdx.x * 4 + (threadIdx.x >> 6);
    int lane = threadIdx.x & 63;
    int i = w >> 5;
    int b = w & 31;
    const float4* wr = (const float4*)(lin_w + (size_t)i * 2 * N);  // 512 float4s per row
    const float4* cr = (const float4*)(content + (size_t)b * N);
    const float4* hr = (const float4*)(hx + (size_t)b * N);
    float acc = 0.f;
    #pragma unroll
    for (int k = 0; k < 4; ++k) {
        float4 a = wr[k * 64 + lane];
        float4 c = cr[k * 64 + lane];
        acc += a.x * c.x + a.y * c.y + a.z * c.z + a.w * c.w;
    }
    #pragma unroll
    for (int k = 0; k < 4; ++k) {
        float4 a = wr[256 + k * 64 + lane];
        float4 h = hr[k * 64 + lane];
        acc += a.x * h.x + a.y * h.y + a.z * h.z + a.w * h.w;
    }
    acc = wave_reduce_sum(acc);
    if (lane == 0) out[(size_t)b * N + i] = fast_tanh(acc + lin_b[i]);
}

extern "C" void kernel_launch(void* const* d_in, const int* in_sizes, int n_in,
                              void* d_out, int out_size, void* d_ws, size_t ws_size,
                              hipStream_t stream) {
    const float* hx    = (const float*)d_in[0];
    const float* eo    = (const float*)d_in[1];
    const float* ef    = (const float*)d_in[2];
    const float* mask  = (const float*)d_in[3];
    const float* Ws_w  = (const float*)d_in[4];
    const float* Ws_b  = (const float*)d_in[5];
    const float* v_w   = (const float*)d_in[6];
    const float* v_b   = (const float*)d_in[7];
    const float* lin_w = (const float*)d_in[8];
    const float* lin_b = (const float*)d_in[9];
    float* out = (float*)d_out;

    float* ws      = (float*)d_ws;
    float* dec     = ws;              // B*N   = 32768 floats
    float* scores  = ws + 32768;      // B*T   = 65536
    float* attn    = ws + 98304;      // B*T   = 65536
    float* content = ws + 163840;     // B*N   = 32768
    // total 196608 floats = 768 KB of ws

    // content is accumulated via atomics — zero it (ws is poisoned each call)
    hipMemsetAsync(content, 0, (size_t)B * N * sizeof(float), stream);

    dec_feature_kernel<<<(B * N) / 4, 256, 0, stream>>>(hx, Ws_w, Ws_b, dec);
    scores_kernel<<<(T * B) / 4, 256, 0, stream>>>(ef, dec, v_w, v_b, scores);
    softmax_kernel<<<B, 256, 0, stream>>>(scores, mask, attn);
    content_kernel<<<dim3(T / 16, B), 256, 0, stream>>>(eo, attn, content);
    out_kernel<<<(B * N) / 4, 256, 0, stream>>>(content, hx, lin_w, lin_b, out);
}

// Round 2
// 561.981 us; speedup vs baseline: 1.0583x; 1.0583x over previous
//
#include <hip/hip_runtime.h>
#include <math.h>

#define T 2048
#define B 32
#define N 1024
#define NCHUNK 64           // t-chunks for content partial sums
#define TCHUNK (T / NCHUNK) // 32 timesteps per chunk

__device__ __forceinline__ float fast_tanh(float x) {
    // 1 - 2/(e^{2x}+1): saturates at +/-1, no NaN at overflow.
    // v_rcp_f32 approx is ~1 ulp — far inside the 2e-2 absmax threshold.
    float e = __expf(2.0f * x);
    return 1.0f - 2.0f * __builtin_amdgcn_rcpf(e + 1.0f);
}

__device__ __forceinline__ float wave_reduce_sum(float v) {
    #pragma unroll
    for (int off = 32; off > 0; off >>= 1) v += __shfl_down(v, off, 64);
    return v;
}

// dec[b][i] = sum_j hx[b][j] * Ws_w[i][j] + Ws_b[i]
__global__ void dec_feature_kernel(const float* __restrict__ hx,
                                   const float* __restrict__ Ws_w,
                                   const float* __restrict__ Ws_b,
                                   float* __restrict__ dec) {
    int w = blockIdx.x * 4 + (threadIdx.x >> 6);
    int lane = threadIdx.x & 63;
    int i = w >> 5;
    int b = w & 31;
    const float4* wr = (const float4*)(Ws_w + (size_t)i * N);
    const float4* hr = (const float4*)(hx + (size_t)b * N);
    float acc = 0.f;
    #pragma unroll
    for (int k = 0; k < 4; ++k) {
        float4 a = wr[k * 64 + lane];
        float4 h = hr[k * 64 + lane];
        acc += a.x * h.x + a.y * h.y + a.z * h.z + a.w * h.w;
    }
    acc = wave_reduce_sum(acc);
    if (lane == 0) dec[(size_t)b * N + i] = acc + Ws_b[i];
}

// scores[b][t] = sum_n tanh(ef[t][b][n] + dec[b][n]) * v_w[n] + v_b
__global__ void scores_kernel(const float* __restrict__ ef,
                              const float* __restrict__ dec,
                              const float* __restrict__ v_w,
                              const float* __restrict__ v_b,
                              float* __restrict__ scores) {
    int w = blockIdx.x * 4 + (threadIdx.x >> 6);  // w = t*B + b (ef flat layout)
    int lane = threadIdx.x & 63;
    int t = w >> 5;
    int b = w & 31;
    const float4* e4 = (const float4*)(ef + (size_t)w * N);
    const float4* d4 = (const float4*)(dec + (size_t)b * N);
    const float4* v4 = (const float4*)v_w;
    float acc = 0.f;
    #pragma unroll
    for (int k = 0; k < 4; ++k) {
        float4 e = e4[k * 64 + lane];
        float4 d = d4[k * 64 + lane];
        float4 v = v4[k * 64 + lane];
        acc += fast_tanh(e.x + d.x) * v.x + fast_tanh(e.y + d.y) * v.y
             + fast_tanh(e.z + d.z) * v.z + fast_tanh(e.w + d.w) * v.w;
    }
    acc = wave_reduce_sum(acc);
    if (lane == 0) scores[(size_t)b * T + t] = acc + v_b[0];
}

// attn[b][t] = softmax_t(scores[b]) * mask[b][t]
__global__ void softmax_kernel(const float* __restrict__ scores,
                               const float* __restrict__ mask,
                               float* __restrict__ attn) {
    int b = blockIdx.x;
    int tid = threadIdx.x;
    int lane = tid & 63, wid = tid >> 6;
    float s[8];
    float m = -1e30f;
    #pragma unroll
    for (int k = 0; k < 8; ++k) {
        s[k] = scores[(size_t)b * T + tid + k * 256];
        m = fmaxf(m, s[k]);
    }
    __shared__ float redm[4], reds[4];
    #pragma unroll
    for (int off = 32; off > 0; off >>= 1) m = fmaxf(m, __shfl_down(m, off, 64));
    if (lane == 0) redm[wid] = m;
    __syncthreads();
    m = fmaxf(fmaxf(redm[0], redm[1]), fmaxf(redm[2], redm[3]));
    float sum = 0.f;
    #pragma unroll
    for (int k = 0; k < 8; ++k) { s[k] = __expf(s[k] - m); sum += s[k]; }
    sum = wave_reduce_sum(sum);
    if (lane == 0) reds[wid] = sum;
    __syncthreads();
    float inv = __builtin_amdgcn_rcpf(reds[0] + reds[1] + reds[2] + reds[3]);
    #pragma unroll
    for (int k = 0; k < 8; ++k)
        attn[(size_t)b * T + tid + k * 256] =
            s[k] * inv * mask[(size_t)b * T + tid + k * 256];
}

// partial[chunk][b][n] = sum_{t in chunk} attn[b][t] * eo[t][b][n]  (no atomics)
__global__ void content_partial_kernel(const float* __restrict__ eo,
                                       const float* __restrict__ attn,
                                       float* __restrict__ partial) {
    int b = blockIdx.y;
    int chunk = blockIdx.x;
    int tid = threadIdx.x;
    const float4* base = (const float4*)eo;
    float4 acc = {0.f, 0.f, 0.f, 0.f};
    #pragma unroll 4
    for (int tt = 0; tt < TCHUNK; ++tt) {
        int t = chunk * TCHUNK + tt;
        float a = attn[(size_t)b * T + t];
        float4 e = base[((size_t)t * B + b) * (N / 4) + tid];
        acc.x += a * e.x; acc.y += a * e.y; acc.z += a * e.z; acc.w += a * e.w;
    }
    ((float4*)partial)[((size_t)chunk * B + b) * (N / 4) + tid] = acc;
}

// content[g] = sum_c partial[c][g]   (g indexes flat B*N)
__global__ void content_reduce_kernel(const float* __restrict__ partial,
                                      float* __restrict__ content) {
    int g = blockIdx.x * 256 + threadIdx.x;  // 0 .. B*N/4-1 (float4 units)
    const float4* p4 = (const float4*)partial;
    float4 acc = {0.f, 0.f, 0.f, 0.f};
    #pragma unroll 8
    for (int c = 0; c < NCHUNK; ++c) {
        float4 v = p4[(size_t)c * (B * N / 4) + g];
        acc.x += v.x; acc.y += v.y; acc.z += v.z; acc.w += v.w;
    }
    ((float4*)content)[g] = acc;
}

// out[b][i] = tanh( dot(content[b], lin_w[i][:N]) + dot(hx[b], lin_w[i][N:]) + lin_b[i] )
__global__ void out_kernel(const float* __restrict__ content,
                           const float* __restrict__ hx,
                           const float* __restrict__ lin_w,
                           const float* __restrict__ lin_b,
                           float* __restrict__ out) {
    int w = blockIdx.x * 4 + (threadIdx.x >> 6);
    int lane = threadIdx.x & 63;
    int i = w >> 5;
    int b = w & 31;
    const float4* wr = (const float4*)(lin_w + (size_t)i * 2 * N);
    const float4* cr = (const float4*)(content + (size_t)b * N);
    const float4* hr = (const float4*)(hx + (size_t)b * N);
    float acc = 0.f;
    #pragma unroll
    for (int k = 0; k < 4; ++k) {
        float4 a = wr[k * 64 + lane];
        float4 c = cr[k * 64 + lane];
        acc += a.x * c.x + a.y * c.y + a.z * c.z + a.w * c.w;
    }
    #pragma unroll
    for (int k = 0; k < 4; ++k) {
        float4 a = wr[256 + k * 64 + lane];
        float4 h = hr[k * 64 + lane];
        acc += a.x * h.x + a.y * h.y + a.z * h.z + a.w * h.w;
    }
    acc = wave_reduce_sum(acc);
    if (lane == 0) out[(size_t)b * N + i] = fast_tanh(acc + lin_b[i]);
}

extern "C" void kernel_launch(void* const* d_in, const int* in_sizes, int n_in,
                              void* d_out, int out_size, void* d_ws, size_t ws_size,
                              hipStream_t stream) {
    const float* hx    = (const float*)d_in[0];
    const float* eo    = (const float*)d_in[1];
    const float* ef    = (const float*)d_in[2];
    const float* mask  = (const float*)d_in[3];
    const float* Ws_w  = (const float*)d_in[4];
    const float* Ws_b  = (const float*)d_in[5];
    const float* v_w   = (const float*)d_in[6];
    const float* v_b   = (const float*)d_in[7];
    const float* lin_w = (const float*)d_in[8];
    const float* lin_b = (const float*)d_in[9];
    float* out = (float*)d_out;

    float* ws      = (float*)d_ws;
    float* dec     = ws;                      // B*N        = 32768 floats
    float* scores  = dec + B * N;             // B*T        = 65536
    float* attn    = scores + B * T;          // B*T        = 65536
    float* content = attn + B * T;            // B*N        = 32768
    float* partial = content + B * N;         // NCHUNK*B*N = 2097152 floats (8 MB)

    dec_feature_kernel<<<(B * N) / 4, 256, 0, stream>>>(hx, Ws_w, Ws_b, dec);
    scores_kernel<<<(T * B) / 4, 256, 0, stream>>>(ef, dec, v_w, v_b, scores);
    softmax_kernel<<<B, 256, 0, stream>>>(scores, mask, attn);
    content_partial_kernel<<<dim3(NCHUNK, B), 256, 0, stream>>>(eo, attn, partial);
    content_reduce_kernel<<<(B * N / 4) / 256, 256, 0, stream>>>(partial, content);
    out_kernel<<<(B * N) / 4, 256, 0, stream>>>(content, hx, lin_w, lin_b, out);
}